// Round 7
// baseline (65.879 us; speedup 1.0000x reference)
//
#include <hip/hip_runtime.h>

#define NQ 12
#define NSTATE (1 << NQ)   // 4096 amps per batch element
#define NL 6
#define TPB 1024           // two batch elements per block, 512 threads each

// Per-element LDS layout: phys = swz(i) = i ^ ((i>>4)&0xF) (R5's empirically
// lowest-conflict swizzle). CNOT-chain Gray permutation new[i]=old[g(i)],
// g(i)=i^(i>>1), applied as a g^-1 scatter at pass-D's store. Gate matrices
// live in lane slots of VGPRs, broadcast via v_readlane (no LDS, no lgkm).

__device__ __forceinline__ float RL(float v, int idx) {
    return __int_as_float(__builtin_amdgcn_readlane(__float_as_int(v), idx));
}

// Rot(phi,theta,omega): u00=(A,-B) u01=(-C,-D) u10=(C,-D) u11=(A,B)
__device__ __forceinline__ void bf_sg(float2& s0, float2& s1,
                                      float A, float B, float C, float D) {
    float2 n0, n1;
    n0.x = fmaf(A, s0.x, fmaf( B, s0.y, fmaf(-C, s1.x,  D * s1.y)));
    n0.y = fmaf(A, s0.y, fmaf(-B, s0.x, fmaf(-C, s1.y, -D * s1.x)));
    n1.x = fmaf(C, s0.x, fmaf( D, s0.y, fmaf( A, s1.x, -B * s1.y)));
    n1.y = fmaf(C, s0.y, fmaf(-D, s0.x, fmaf( A, s1.y,  B * s1.x)));
    s0 = n0; s1 = n1;
}

#define BF(i,j) bf_sg(a##i, a##j, A, B, C, D)
#define P8K0 BF(0,1); BF(2,3); BF(4,5); BF(6,7);
#define P8K1 BF(0,2); BF(1,3); BF(4,6); BF(5,7);
#define P8K2 BF(0,4); BF(1,5); BF(2,6); BF(3,7);
#define GATE(qq, P) { const int gi = gb + (qq); \
    const float A = RL(uA, gi), B = RL(uB, gi), \
                C = RL(uC, gi), D = RL(uD, gi); P }

#define LD8(ADR) { a0=stp[ADR(0)]; a1=stp[ADR(1)]; a2=stp[ADR(2)]; a3=stp[ADR(3)]; \
                   a4=stp[ADR(4)]; a5=stp[ADR(5)]; a6=stp[ADR(6)]; a7=stp[ADR(7)]; }
#define ST8(ADR) { stp[ADR(0)]=a0; stp[ADR(1)]=a1; stp[ADR(2)]=a2; stp[ADR(3)]=a3; \
                   stp[ADR(4)]=a4; stp[ADR(5)]=a5; stp[ADR(6)]=a6; stp[ADR(7)]=a7; }

// Pass tilings (i = logical index, t = 9-bit half-thread, r = 3-bit reg):
// A: i=(r<<9)|t   B: i=t[8:6]<<9|r<<6|t[5:0]   C: i=t[8:3]<<6|r<<3|t[2:0]
// D: i=(t<<3)|r   D-scatter: phys = swz(g^-1(i))
#define ADRA(r)  (ptA + ((r) << 9))                       // folds to offset-imm
#define ADRB(r)  (ptB ^ ((r) << 6) ^ (((r) & 3) << 2))
#define ADRC(r)  (ptC ^ ((r) << 3) ^ ((r) >> 1))
#define ADRD(r)  (ptD ^ (r))
#define GINV3(r) ((r) ^ ((r) >> 1) ^ ((r) >> 2))
#define ADRDS(r) (ptDS ^ GINV3(r))

#define INITR(r) { const float m = mlow * f##r; \
    const int pc = (pcl + __popc(r)) & 3; \
    a##r = make_float2((pc==0) ? m : ((pc==2) ? -m : 0.0f), \
                       (pc==1) ? -m : ((pc==3) ? m : 0.0f)); }

__global__ __launch_bounds__(TPB) void qsim_kernel(
    const float* __restrict__ x,      // (B, 12)
    const float* __restrict__ w,      // (6, 12, 3)
    const float* __restrict__ hw,     // (2, 1)
    const float* __restrict__ hb,     // (2,)
    float* __restrict__ out)          // (B, 2)
{
    __shared__ float2 st[2 * NSTATE]; // 64 KB: two independent 32 KB states

    const int tid  = threadIdx.x;
    const int h    = tid >> 9;        // which batch element of this block
    const int t    = tid & 511;       // 9-bit index within the element
    const int b    = blockIdx.x * 2 + h;
    const int lane = tid & 63;
    float2* stp = st + h * NSTATE;

    // ---- prologue: 72 gate-constant quads into lane slots ----
    // lane j: gate j (0..63); lanes 52..63 second set: gates 60..71.
    float gA, gB, gC, gD;
    float gA2 = 0.f, gB2 = 0.f, gC2 = 0.f, gD2 = 0.f;
    {
        const float* wl = w + lane * 3;
        float phi = wl[0], th = wl[1], om = wl[2];
        float c, s, ca, sa, cb, sb;
        __sincosf(0.5f * th, &s, &c);
        __sincosf(0.5f * (phi + om), &sa, &ca);
        __sincosf(0.5f * (phi - om), &sb, &cb);
        gA = c * ca; gB = c * sa; gC = s * cb; gD = s * sb;
        if (lane >= 52) {
            const float* wl2 = w + (lane + 8) * 3;
            float phi2 = wl2[0], th2 = wl2[1], om2 = wl2[2];
            float c2, s2q, ca2, sa2, cb2, sb2;
            __sincosf(0.5f * th2, &s2q, &c2);
            __sincosf(0.5f * (phi2 + om2), &sa2, &ca2);
            __sincosf(0.5f * (phi2 - om2), &sb2, &cb2);
            gA2 = c2 * ca2; gB2 = c2 * sa2; gC2 = s2q * cb2; gD2 = s2q * sb2;
        }
    }

    // ---- loop-invariant address bases (phys = swz(i) = i ^ ((i>>4)&0xF)) ----
    const int ptA = t ^ ((t >> 4) & 0xF);
    const int ptB = (((t & 0x1C0) << 3) | (t & 0x3F)) ^ ((t >> 4) & 0x3);
    const int ptC = (((t & 0x1F8) << 3) | (t & 0x7)) ^ (((t >> 3) & 0x3) << 2);
    const int ptD = (t << 3) ^ ((t >> 1) & 0xF);
    int gv = t << 3;                  // g^-1 = suffix parity (GF(2)-linear)
    gv ^= gv >> 1; gv ^= gv >> 2; gv ^= gv >> 4; gv ^= gv >> 8; gv &= 0xFFF;
    const int ptDS = gv ^ ((gv >> 4) & 0xF);

    float2 a0, a1, a2, a3, a4, a5, a6, a7;

    #pragma unroll 1
    for (int L = 0; L < NL; ++L) {
        const int   gb = (L == 5) ? 52 : L * 12;
        const float uA = (L == 5) ? gA2 : gA;
        const float uB = (L == 5) ? gB2 : gB;
        const float uC = (L == 5) ? gC2 : gC;
        const float uD = (L == 5) ? gD2 : gD;

        // ---- Pass A: state bits 11..9 (qubits 0..2) ----
        if (L == 0) {
            // per-thread embedding sincos + product state in regs
            float c0,s0,c1,s1,c2,s2,c3,s3,c4,s4,c5,s5;
            float c6,s6,c7,s7,c8,s8,c9,s9,c10,s10,c11,s11;
            #define EMB(q) __sincosf(0.5f * x[b * NQ + (q)], &s##q, &c##q);
            EMB(0) EMB(1) EMB(2) EMB(3) EMB(4)  EMB(5)
            EMB(6) EMB(7) EMB(8) EMB(9) EMB(10) EMB(11)
            #undef EMB
            // t bit j = state bit j <-> qubit 11-j
            float mlow = ((t & 1)   ? s11 : c11) * ((t & 2)   ? s10 : c10);
            mlow *= ((t & 4)   ? s9 : c9) * ((t & 8)   ? s8 : c8);
            mlow *= ((t & 16)  ? s7 : c7) * ((t & 32)  ? s6 : c6);
            mlow *= ((t & 64)  ? s5 : c5) * ((t & 128) ? s4 : c4);
            mlow *= ((t & 256) ? s3 : c3);
            // reg bit k <-> qubit 2-k
            const float e0 = c1 * c0, e1 = s1 * c0, e2 = c1 * s0, e3 = s1 * s0;
            const float f0 = c2 * e0, f1 = s2 * e0, f2 = c2 * e1, f3 = s2 * e1;
            const float f4 = c2 * e2, f5 = s2 * e2, f6 = c2 * e3, f7 = s2 * e3;
            const int pcl = __popc(t);
            INITR(0) INITR(1) INITR(2) INITR(3)
            INITR(4) INITR(5) INITR(6) INITR(7)
        } else {
            LD8(ADRA)                 // rd == wr set per thread
        }
        GATE(2, P8K0) GATE(1, P8K1) GATE(0, P8K2)
        ST8(ADRA)
        __syncthreads();

        // ---- Pass B: state bits 8..6 (qubits 3..5) ----
        LD8(ADRB)
        GATE(5, P8K0) GATE(4, P8K1) GATE(3, P8K2)
        ST8(ADRB)
        __syncthreads();

        // ---- Pass C: state bits 5..3 (qubits 6..8) ----
        LD8(ADRC)
        GATE(8, P8K0) GATE(7, P8K1) GATE(6, P8K2)
        ST8(ADRC)
        __syncthreads();

        // ---- Pass D: state bits 2..0 (qubits 9..11) ----
        LD8(ADRD)
        GATE(11, P8K0) GATE(10, P8K1) GATE(9, P8K2)
        if (L < NL - 1) {
            __syncthreads();          // all pass-D reads done before scatter
            ST8(ADRDS)                // Gray perm via g^-1 scatter
            __syncthreads();
        }
        // last layer: measure from regs (trailing perm preserves bit 11)
    }

    // ---- measurement: <Z> on qubit 0 = state bit 11 = t bit 8 ----
    float zsum = 0.0f;
    zsum += a0.x*a0.x + a0.y*a0.y;  zsum += a1.x*a1.x + a1.y*a1.y;
    zsum += a2.x*a2.x + a2.y*a2.y;  zsum += a3.x*a3.x + a3.y*a3.y;
    zsum += a4.x*a4.x + a4.y*a4.y;  zsum += a5.x*a5.x + a5.y*a5.y;
    zsum += a6.x*a6.x + a6.y*a6.y;  zsum += a7.x*a7.x + a7.y*a7.y;

    float z = (t & 256) ? -zsum : zsum;
    #pragma unroll
    for (int off = 32; off >= 1; off >>= 1)
        z += __shfl_down(z, off);

    __syncthreads();                  // all pass-D reads done before st reuse
    float* red = (float*)stp;         // per-half scratch
    if (lane == 0) red[t >> 6] = z;
    __syncthreads();

    if (t == 0) {
        float zt = 0.0f;
        #pragma unroll
        for (int wv = 0; wv < 8; ++wv) zt += red[wv];
        out[2 * b + 0] = zt * hw[0] + hb[0];
        out[2 * b + 1] = zt * hw[1] + hb[1];
    }
}

extern "C" void kernel_launch(void* const* d_in, const int* in_sizes, int n_in,
                              void* d_out, int out_size, void* d_ws, size_t ws_size,
                              hipStream_t stream) {
    const float* x  = (const float*)d_in[0];
    const float* w  = (const float*)d_in[1];
    const float* hw = (const float*)d_in[2];
    const float* hb = (const float*)d_in[3];
    float* out = (float*)d_out;
    const int B = in_sizes[0] / NQ;   // 1024
    qsim_kernel<<<B / 2, TPB, 0, stream>>>(x, w, hw, hb, out);
}

// Round 8
// 61.716 us; speedup vs baseline: 1.0674x; 1.0674x over previous
//
#include <hip/hip_runtime.h>

#define NQ 12
#define NSTATE (1 << NQ)   // 4096 amps per batch element
#define NL 6
#define TPB 512            // 8 amps/thread/element, TWO elements per block

// Per-element LDS layout: phys = swz(i) = i ^ ((i>>4)&0xF). CNOT-chain Gray
// permutation new[i]=old[g(i)], g(i)=i^(i>>1), applied as a g^-1 scatter at
// pass-D's store. Gate matrices in lane slots, broadcast via v_readlane.
// Two batch elements interleaved per thread: element 1 lives at st[+NSTATE],
// a compile-time +32KB that folds into the ds-instruction offset field.

__device__ __forceinline__ float RL(float v, int idx) {
    return __int_as_float(__builtin_amdgcn_readlane(__float_as_int(v), idx));
}

// Rot(phi,theta,omega): u00=(A,-B) u01=(-C,-D) u10=(C,-D) u11=(A,B)
__device__ __forceinline__ void bf_sg(float2& s0, float2& s1,
                                      float A, float B, float C, float D) {
    float2 n0, n1;
    n0.x = fmaf(A, s0.x, fmaf( B, s0.y, fmaf(-C, s1.x,  D * s1.y)));
    n0.y = fmaf(A, s0.y, fmaf(-B, s0.x, fmaf(-C, s1.y, -D * s1.x)));
    n1.x = fmaf(C, s0.x, fmaf( D, s0.y, fmaf( A, s1.x, -B * s1.y)));
    n1.y = fmaf(C, s0.y, fmaf(-D, s0.x, fmaf( A, s1.y,  B * s1.x)));
    s0 = n0; s1 = n1;
}

#define BFA(i,j) bf_sg(a##i, a##j, A, B, C, D)
#define BFB(i,j) bf_sg(b##i, b##j, A, B, C, D)
#define PA_K0 BFA(0,1); BFA(2,3); BFA(4,5); BFA(6,7);
#define PA_K1 BFA(0,2); BFA(1,3); BFA(4,6); BFA(5,7);
#define PA_K2 BFA(0,4); BFA(1,5); BFA(2,6); BFA(3,7);
#define PB_K0 BFB(0,1); BFB(2,3); BFB(4,5); BFB(6,7);
#define PB_K1 BFB(0,2); BFB(1,3); BFB(4,6); BFB(5,7);
#define PB_K2 BFB(0,4); BFB(1,5); BFB(2,6); BFB(3,7);
// one readlane broadcast feeds both elements' butterflies
#define GATE2(qq, PKA, PKB) { const int gi = gb + (qq); \
    const float A = RL(uA, gi), B = RL(uB, gi), \
                C = RL(uC, gi), D = RL(uD, gi); PKA PKB }

#define LD8A(ADR) { a0=st[ADR(0)]; a1=st[ADR(1)]; a2=st[ADR(2)]; a3=st[ADR(3)]; \
                    a4=st[ADR(4)]; a5=st[ADR(5)]; a6=st[ADR(6)]; a7=st[ADR(7)]; }
#define LD8B(ADR) { b0=st[ADR(0)+NSTATE]; b1=st[ADR(1)+NSTATE]; \
                    b2=st[ADR(2)+NSTATE]; b3=st[ADR(3)+NSTATE]; \
                    b4=st[ADR(4)+NSTATE]; b5=st[ADR(5)+NSTATE]; \
                    b6=st[ADR(6)+NSTATE]; b7=st[ADR(7)+NSTATE]; }
#define ST8A(ADR) { st[ADR(0)]=a0; st[ADR(1)]=a1; st[ADR(2)]=a2; st[ADR(3)]=a3; \
                    st[ADR(4)]=a4; st[ADR(5)]=a5; st[ADR(6)]=a6; st[ADR(7)]=a7; }
#define ST8B(ADR) { st[ADR(0)+NSTATE]=b0; st[ADR(1)+NSTATE]=b1; \
                    st[ADR(2)+NSTATE]=b2; st[ADR(3)+NSTATE]=b3; \
                    st[ADR(4)+NSTATE]=b4; st[ADR(5)+NSTATE]=b5; \
                    st[ADR(6)+NSTATE]=b6; st[ADR(7)+NSTATE]=b7; }

// Pass tilings (i = logical index, t = 9-bit thread, r = 3-bit reg):
// A: i=(r<<9)|t   B: i=t[8:6]<<9|r<<6|t[5:0]   C: i=t[8:3]<<6|r<<3|t[2:0]
// D: i=(t<<3)|r   D-scatter: phys = swz(g^-1(i))
#define ADRA(r)  (ptA + ((r) << 9))                       // folds to offset-imm
#define ADRB(r)  (ptB ^ ((r) << 6) ^ (((r) & 3) << 2))
#define ADRC(r)  (ptC ^ ((r) << 3) ^ ((r) >> 1))
#define ADRD(r)  (ptD ^ (r))
#define GINV3(r) ((r) ^ ((r) >> 1) ^ ((r) >> 2))
#define ADRDS(r) (ptDS ^ GINV3(r))

#define INITR(P, r) { const float m = mlow * f##r; \
    const int pc = (pcl + __popc(r)) & 3; \
    P##r = make_float2((pc==0) ? m : ((pc==2) ? -m : 0.0f), \
                       (pc==1) ? -m : ((pc==3) ? m : 0.0f)); }

__global__ __launch_bounds__(TPB) void qsim_kernel(
    const float* __restrict__ x,      // (B, 12)
    const float* __restrict__ w,      // (6, 12, 3)
    const float* __restrict__ hw,     // (2, 1)
    const float* __restrict__ hb,     // (2,)
    float* __restrict__ out)          // (B, 2)
{
    __shared__ float2 st[2 * NSTATE]; // 64 KB: two elements' states

    const int t    = threadIdx.x;     // 9 bits
    const int lane = t & 63;
    const int e0   = blockIdx.x * 2;  // first batch element of this block

    // ---- prologue: 72 gate-constant quads into lane slots ----
    float gA, gB, gC, gD;
    float gA2 = 0.f, gB2 = 0.f, gC2 = 0.f, gD2 = 0.f;
    {
        const float* wl = w + lane * 3;
        float phi = wl[0], th = wl[1], om = wl[2];
        float c, s, ca, sa, cb, sb;
        __sincosf(0.5f * th, &s, &c);
        __sincosf(0.5f * (phi + om), &sa, &ca);
        __sincosf(0.5f * (phi - om), &sb, &cb);
        gA = c * ca; gB = c * sa; gC = s * cb; gD = s * sb;
        if (lane >= 52) {
            const float* wl2 = w + (lane + 8) * 3;
            float phi2 = wl2[0], th2 = wl2[1], om2 = wl2[2];
            float c2, s2q, ca2, sa2, cb2, sb2;
            __sincosf(0.5f * th2, &s2q, &c2);
            __sincosf(0.5f * (phi2 + om2), &sa2, &ca2);
            __sincosf(0.5f * (phi2 - om2), &sb2, &cb2);
            gA2 = c2 * ca2; gB2 = c2 * sa2; gC2 = s2q * cb2; gD2 = s2q * sb2;
        }
    }

    // ---- loop-invariant address bases (phys = swz(i) = i ^ ((i>>4)&0xF)) ----
    const int ptA = t ^ ((t >> 4) & 0xF);
    const int ptB = (((t & 0x1C0) << 3) | (t & 0x3F)) ^ ((t >> 4) & 0x3);
    const int ptC = (((t & 0x1F8) << 3) | (t & 0x7)) ^ (((t >> 3) & 0x3) << 2);
    const int ptD = (t << 3) ^ ((t >> 1) & 0xF);
    int gv = t << 3;                  // g^-1 = suffix parity (GF(2)-linear)
    gv ^= gv >> 1; gv ^= gv >> 2; gv ^= gv >> 4; gv ^= gv >> 8; gv &= 0xFFF;
    const int ptDS = gv ^ ((gv >> 4) & 0xF);

    float2 a0, a1, a2, a3, a4, a5, a6, a7;   // element 0 state
    float2 b0, b1, b2, b3, b4, b5, b6, b7;   // element 1 state

    #pragma unroll 1
    for (int L = 0; L < NL; ++L) {
        const int   gb = (L == 5) ? 52 : L * 12;
        const float uA = (L == 5) ? gA2 : gA;
        const float uB = (L == 5) ? gB2 : gB;
        const float uC = (L == 5) ? gC2 : gC;
        const float uD = (L == 5) ? gD2 : gD;

        // ---- Pass A: state bits 11..9 (qubits 0..2) ----
        if (L == 0) {
            const int pcl = __popc(t);
            {   // element 0 init: amp_i = (-i)^popc(i) * prod(cos/sin)
                const float* xb = x + e0 * NQ;
                float c0,s0,c1,s1,c2,s2,c3,s3,c4,s4,c5,s5;
                float c6,s6,c7,s7,c8,s8,c9,s9,c10,s10,c11,s11;
                #define EMB(q) __sincosf(0.5f * xb[q], &s##q, &c##q);
                EMB(0) EMB(1) EMB(2) EMB(3) EMB(4)  EMB(5)
                EMB(6) EMB(7) EMB(8) EMB(9) EMB(10) EMB(11)
                float mlow = ((t & 1)   ? s11 : c11) * ((t & 2)   ? s10 : c10);
                mlow *= ((t & 4)   ? s9 : c9) * ((t & 8)   ? s8 : c8);
                mlow *= ((t & 16)  ? s7 : c7) * ((t & 32)  ? s6 : c6);
                mlow *= ((t & 64)  ? s5 : c5) * ((t & 128) ? s4 : c4);
                mlow *= ((t & 256) ? s3 : c3);
                const float e_0 = c1*c0, e_1 = s1*c0, e_2 = c1*s0, e_3 = s1*s0;
                const float f0 = c2*e_0, f1 = s2*e_0, f2 = c2*e_1, f3 = s2*e_1;
                const float f4 = c2*e_2, f5 = s2*e_2, f6 = c2*e_3, f7 = s2*e_3;
                INITR(a,0) INITR(a,1) INITR(a,2) INITR(a,3)
                INITR(a,4) INITR(a,5) INITR(a,6) INITR(a,7)
            }
            {   // element 1 init
                const float* xb = x + (e0 + 1) * NQ;
                float c0,s0,c1,s1,c2,s2,c3,s3,c4,s4,c5,s5;
                float c6,s6,c7,s7,c8,s8,c9,s9,c10,s10,c11,s11;
                EMB(0) EMB(1) EMB(2) EMB(3) EMB(4)  EMB(5)
                EMB(6) EMB(7) EMB(8) EMB(9) EMB(10) EMB(11)
                #undef EMB
                float mlow = ((t & 1)   ? s11 : c11) * ((t & 2)   ? s10 : c10);
                mlow *= ((t & 4)   ? s9 : c9) * ((t & 8)   ? s8 : c8);
                mlow *= ((t & 16)  ? s7 : c7) * ((t & 32)  ? s6 : c6);
                mlow *= ((t & 64)  ? s5 : c5) * ((t & 128) ? s4 : c4);
                mlow *= ((t & 256) ? s3 : c3);
                const float e_0 = c1*c0, e_1 = s1*c0, e_2 = c1*s0, e_3 = s1*s0;
                const float f0 = c2*e_0, f1 = s2*e_0, f2 = c2*e_1, f3 = s2*e_1;
                const float f4 = c2*e_2, f5 = s2*e_2, f6 = c2*e_3, f7 = s2*e_3;
                INITR(b,0) INITR(b,1) INITR(b,2) INITR(b,3)
                INITR(b,4) INITR(b,5) INITR(b,6) INITR(b,7)
            }
        } else {
            LD8A(ADRA)
            LD8B(ADRA)
        }
        GATE2(2, PA_K0, PB_K0) GATE2(1, PA_K1, PB_K1) GATE2(0, PA_K2, PB_K2)
        ST8A(ADRA) ST8B(ADRA)
        __syncthreads();

        // ---- Pass B: state bits 8..6 (qubits 3..5) ----
        LD8A(ADRB) LD8B(ADRB)
        GATE2(5, PA_K0, PB_K0) GATE2(4, PA_K1, PB_K1) GATE2(3, PA_K2, PB_K2)
        ST8A(ADRB) ST8B(ADRB)
        __syncthreads();

        // ---- Pass C: state bits 5..3 (qubits 6..8) ----
        LD8A(ADRC) LD8B(ADRC)
        GATE2(8, PA_K0, PB_K0) GATE2(7, PA_K1, PB_K1) GATE2(6, PA_K2, PB_K2)
        ST8A(ADRC) ST8B(ADRC)
        __syncthreads();

        // ---- Pass D: state bits 2..0 (qubits 9..11) ----
        LD8A(ADRD) LD8B(ADRD)
        GATE2(11, PA_K0, PB_K0) GATE2(10, PA_K1, PB_K1) GATE2(9, PA_K2, PB_K2)
        if (L < NL - 1) {
            __syncthreads();          // all pass-D reads done before scatter
            ST8A(ADRDS) ST8B(ADRDS)   // Gray perm via g^-1 scatter
            __syncthreads();
        }
        // last layer: measure from regs (trailing perm preserves bit 11)
    }

    // ---- measurement: <Z> on qubit 0 = state bit 11 = t bit 8 ----
    float za = 0.0f, zb = 0.0f;
    za += a0.x*a0.x + a0.y*a0.y;  za += a1.x*a1.x + a1.y*a1.y;
    za += a2.x*a2.x + a2.y*a2.y;  za += a3.x*a3.x + a3.y*a3.y;
    za += a4.x*a4.x + a4.y*a4.y;  za += a5.x*a5.x + a5.y*a5.y;
    za += a6.x*a6.x + a6.y*a6.y;  za += a7.x*a7.x + a7.y*a7.y;
    zb += b0.x*b0.x + b0.y*b0.y;  zb += b1.x*b1.x + b1.y*b1.y;
    zb += b2.x*b2.x + b2.y*b2.y;  zb += b3.x*b3.x + b3.y*b3.y;
    zb += b4.x*b4.x + b4.y*b4.y;  zb += b5.x*b5.x + b5.y*b5.y;
    zb += b6.x*b6.x + b6.y*b6.y;  zb += b7.x*b7.x + b7.y*b7.y;

    const float sgn = (t & 256) ? -1.0f : 1.0f;
    za *= sgn; zb *= sgn;
    #pragma unroll
    for (int off = 32; off >= 1; off >>= 1) {
        za += __shfl_down(za, off);
        zb += __shfl_down(zb, off);
    }

    __syncthreads();                  // all pass-D reads done before st reuse
    float* red = (float*)st;
    if (lane == 0) { red[t >> 6] = za; red[8 + (t >> 6)] = zb; }
    __syncthreads();

    if (t == 0) {
        float zta = 0.0f, ztb = 0.0f;
        #pragma unroll
        for (int wv = 0; wv < 8; ++wv) { zta += red[wv]; ztb += red[8 + wv]; }
        out[2 * e0 + 0] = zta * hw[0] + hb[0];
        out[2 * e0 + 1] = zta * hw[1] + hb[1];
        out[2 * e0 + 2] = ztb * hw[0] + hb[0];
        out[2 * e0 + 3] = ztb * hw[1] + hb[1];
    }
}

extern "C" void kernel_launch(void* const* d_in, const int* in_sizes, int n_in,
                              void* d_out, int out_size, void* d_ws, size_t ws_size,
                              hipStream_t stream) {
    const float* x  = (const float*)d_in[0];
    const float* w  = (const float*)d_in[1];
    const float* hw = (const float*)d_in[2];
    const float* hb = (const float*)d_in[3];
    float* out = (float*)d_out;
    const int B = in_sizes[0] / NQ;   // 1024
    qsim_kernel<<<B / 2, TPB, 0, stream>>>(x, w, hw, hb, out);
}

// Round 9
// 54.207 us; speedup vs baseline: 1.2153x; 1.1385x over previous
//
#include <hip/hip_runtime.h>

#define NQ 12
#define NSTATE (1 << NQ)   // 4096 amps per batch element
#define NL 6
#define TPB 512            // 8 amp-slots/thread; TWO batch elements packed/lane

// Two batch elements ride in the two halves of packed-fp32 (v_pk_fma_f32)
// vectors: slot s holds (reA,reB,imA,imB) as one float4 LDS word (b128).
// Same gates + constants apply to both elements -> pure broadcast packed FMA,
// no op_sel shuffles. LDS layout phys = swz(i) = i ^ ((i>>4)&0xF); CNOT-chain
// Gray perm new[i]=old[g(i)], g(i)=i^(i>>1), applied as g^-1 scatter at pass-D
// store. Gate constants in lane slots, broadcast via v_readlane.

typedef float f2 __attribute__((ext_vector_type(2)));
typedef float f4 __attribute__((ext_vector_type(4)));

struct Amp { f2 re, im; };

__device__ __forceinline__ f2 fma2(f2 a, f2 b, f2 c) {
    return __builtin_elementwise_fma(a, b, c);
}
__device__ __forceinline__ float RL(float v, int idx) {
    return __int_as_float(__builtin_amdgcn_readlane(__float_as_int(v), idx));
}

// Rot(phi,theta,omega): u00=(A,-B) u01=(-C,-D) u10=(C,-D) u11=(A,B)
__device__ __forceinline__ void bf_pk(Amp& s0, Amp& s1, f2 A, f2 B, f2 C, f2 D) {
    f2 n0re = fma2(A, s0.re, fma2(B, s0.im, fma2(C, -s1.re,  D * s1.im)));
    f2 n0im = fma2(A, s0.im, fma2(-B, s0.re, fma2(C, -s1.im, -D * s1.re)));
    f2 n1re = fma2(C, s0.re, fma2(D, s0.im, fma2(A,  s1.re, -B * s1.im)));
    f2 n1im = fma2(C, s0.im, fma2(-D, s0.re, fma2(A,  s1.im,  B * s1.re)));
    s0.re = n0re; s0.im = n0im; s1.re = n1re; s1.im = n1im;
}

#define BF(i,j) bf_pk(a##i, a##j, A, B, C, D)
#define PK0 BF(0,1); BF(2,3); BF(4,5); BF(6,7);
#define PK1 BF(0,2); BF(1,3); BF(4,6); BF(5,7);
#define PK2 BF(0,4); BF(1,5); BF(2,6); BF(3,7);
#define GATE(qq, P) { const int gi = gb + (qq); \
    const float As = RL(uA, gi), Bs = RL(uB, gi), \
                Cs = RL(uC, gi), Ds = RL(uD, gi); \
    const f2 A = {As, As}, B = {Bs, Bs}, C = {Cs, Cs}, D = {Ds, Ds}; P }

#define LD1(r, ADR) { f4 v = st[ADR(r)]; a##r.re = v.xy; a##r.im = v.zw; }
#define ST1(r, ADR) { f4 v; v.xy = a##r.re; v.zw = a##r.im; st[ADR(r)] = v; }
#define LD8(ADR) { LD1(0,ADR) LD1(1,ADR) LD1(2,ADR) LD1(3,ADR) \
                   LD1(4,ADR) LD1(5,ADR) LD1(6,ADR) LD1(7,ADR) }
#define ST8(ADR) { ST1(0,ADR) ST1(1,ADR) ST1(2,ADR) ST1(3,ADR) \
                   ST1(4,ADR) ST1(5,ADR) ST1(6,ADR) ST1(7,ADR) }

// Pass tilings (i = logical index, t = 9-bit thread, r = 3-bit reg):
// A: i=(r<<9)|t   B: i=t[8:6]<<9|r<<6|t[5:0]   C: i=t[8:3]<<6|r<<3|t[2:0]
// D: i=(t<<3)|r   D-scatter: phys = swz(g^-1(i))
#define ADRA(r)  (ptA + ((r) << 9))                       // folds to offset-imm
#define ADRB(r)  (ptB ^ ((r) << 6) ^ (((r) & 3) << 2))
#define ADRC(r)  (ptC ^ ((r) << 3) ^ ((r) >> 1))
#define ADRD(r)  (ptD ^ (r))
#define GINV3(r) ((r) ^ ((r) >> 1) ^ ((r) >> 2))
#define ADRDS(r) (ptDS ^ GINV3(r))

#define INITR(r) { const f2 m = mlow2 * f##r; \
    const int pc = (pcl + __popc(r)) & 3; \
    a##r.re = (pc == 0) ? m : ((pc == 2) ? -m : zero2); \
    a##r.im = (pc == 1) ? -m : ((pc == 3) ? m : zero2); }

__global__ __launch_bounds__(TPB) void qsim_kernel(
    const float* __restrict__ x,      // (B, 12)
    const float* __restrict__ w,      // (6, 12, 3)
    const float* __restrict__ hw,     // (2, 1)
    const float* __restrict__ hb,     // (2,)
    float* __restrict__ out)          // (B, 2)
{
    __shared__ f4 st[NSTATE];         // 64 KB: both elements, packed per slot

    const int t    = threadIdx.x;     // 9 bits
    const int lane = t & 63;
    const int e0   = blockIdx.x * 2;  // first batch element of this block

    // ---- prologue: 72 gate-constant quads into lane slots ----
    float gA, gB, gC, gD;
    float gA2 = 0.f, gB2 = 0.f, gC2 = 0.f, gD2 = 0.f;
    {
        const float* wl = w + lane * 3;
        float phi = wl[0], th = wl[1], om = wl[2];
        float c, s, ca, sa, cb, sb;
        __sincosf(0.5f * th, &s, &c);
        __sincosf(0.5f * (phi + om), &sa, &ca);
        __sincosf(0.5f * (phi - om), &sb, &cb);
        gA = c * ca; gB = c * sa; gC = s * cb; gD = s * sb;
        if (lane >= 52) {
            const float* wl2 = w + (lane + 8) * 3;
            float phi2 = wl2[0], th2 = wl2[1], om2 = wl2[2];
            float c2, s2q, ca2, sa2, cb2, sb2;
            __sincosf(0.5f * th2, &s2q, &c2);
            __sincosf(0.5f * (phi2 + om2), &sa2, &ca2);
            __sincosf(0.5f * (phi2 - om2), &sb2, &cb2);
            gA2 = c2 * ca2; gB2 = c2 * sa2; gC2 = s2q * cb2; gD2 = s2q * sb2;
        }
    }

    // ---- loop-invariant address bases (phys = swz(i) = i ^ ((i>>4)&0xF)) ----
    const int ptA = t ^ ((t >> 4) & 0xF);
    const int ptB = (((t & 0x1C0) << 3) | (t & 0x3F)) ^ ((t >> 4) & 0x3);
    const int ptC = (((t & 0x1F8) << 3) | (t & 0x7)) ^ (((t >> 3) & 0x3) << 2);
    const int ptD = (t << 3) ^ ((t >> 1) & 0xF);
    int gv = t << 3;                  // g^-1 = suffix parity (GF(2)-linear)
    gv ^= gv >> 1; gv ^= gv >> 2; gv ^= gv >> 4; gv ^= gv >> 8; gv &= 0xFFF;
    const int ptDS = gv ^ ((gv >> 4) & 0xF);

    Amp a0, a1, a2, a3, a4, a5, a6, a7;
    const f2 zero2 = {0.f, 0.f};

    #pragma unroll 1
    for (int L = 0; L < NL; ++L) {
        const int   gb = (L == 5) ? 52 : L * 12;
        const float uA = (L == 5) ? gA2 : gA;
        const float uB = (L == 5) ? gB2 : gB;
        const float uC = (L == 5) ? gC2 : gC;
        const float uD = (L == 5) ? gD2 : gD;

        // ---- Pass A: state bits 11..9 (qubits 0..2) ----
        if (L == 0) {
            // packed embedding: both elements' sincos side by side
            const float* xa = x + e0 * NQ;
            const float* xb = x + (e0 + 1) * NQ;
            f2 c0,s0,c1,s1,c2,s2,c3,s3,c4,s4,c5,s5;
            f2 c6,s6,c7,s7,c8,s8,c9,s9,c10,s10,c11,s11;
            #define EMB(q) { float cA_, sA_, cB_, sB_; \
                __sincosf(0.5f * xa[q], &sA_, &cA_); \
                __sincosf(0.5f * xb[q], &sB_, &cB_); \
                c##q = (f2){cA_, cB_}; s##q = (f2){sA_, sB_}; }
            EMB(0) EMB(1) EMB(2) EMB(3) EMB(4)  EMB(5)
            EMB(6) EMB(7) EMB(8) EMB(9) EMB(10) EMB(11)
            #undef EMB
            // t bit j = state bit j <-> qubit 11-j
            f2 mlow2 = ((t & 1)   ? s11 : c11) * ((t & 2)   ? s10 : c10);
            mlow2 = mlow2 * ((t & 4)   ? s9 : c9) * ((t & 8)   ? s8 : c8);
            mlow2 = mlow2 * ((t & 16)  ? s7 : c7) * ((t & 32)  ? s6 : c6);
            mlow2 = mlow2 * ((t & 64)  ? s5 : c5) * ((t & 128) ? s4 : c4);
            mlow2 = mlow2 * ((t & 256) ? s3 : c3);
            // reg bit k <-> qubit 2-k
            const f2 e_0 = c1*c0, e_1 = s1*c0, e_2 = c1*s0, e_3 = s1*s0;
            const f2 f0 = c2*e_0, f1 = s2*e_0, f2_ = c2*e_1, f3 = s2*e_1;
            const f2 f4 = c2*e_2, f5 = s2*e_2, f6 = c2*e_3, f7 = s2*e_3;
            #define f2v f2_
            const int pcl = __popc(t);
            INITR(0) INITR(1) { const f2 m = mlow2 * f2v;   // INITR(2) inline
                const int pc = (pcl + __popc(2)) & 3;
                a2.re = (pc == 0) ? m : ((pc == 2) ? -m : zero2);
                a2.im = (pc == 1) ? -m : ((pc == 3) ? m : zero2); }
            INITR(3) INITR(4) INITR(5) INITR(6) INITR(7)
            #undef f2v
        } else {
            LD8(ADRA)
        }
        GATE(2, PK0) GATE(1, PK1) GATE(0, PK2)
        ST8(ADRA)
        __syncthreads();

        // ---- Pass B: state bits 8..6 (qubits 3..5) ----
        LD8(ADRB)
        GATE(5, PK0) GATE(4, PK1) GATE(3, PK2)
        ST8(ADRB)
        __syncthreads();

        // ---- Pass C: state bits 5..3 (qubits 6..8) ----
        LD8(ADRC)
        GATE(8, PK0) GATE(7, PK1) GATE(6, PK2)
        ST8(ADRC)
        __syncthreads();

        // ---- Pass D: state bits 2..0 (qubits 9..11) ----
        LD8(ADRD)
        GATE(11, PK0) GATE(10, PK1) GATE(9, PK2)
        if (L < NL - 1) {
            __syncthreads();          // all pass-D reads done before scatter
            ST8(ADRDS)                // Gray perm via g^-1 scatter
            __syncthreads();
        }
        // last layer: measure from regs (trailing perm preserves bit 11)
    }

    // ---- measurement: <Z> on qubit 0 = state bit 11 = t bit 8 ----
    f2 zs = zero2;
    zs = fma2(a0.re, a0.re, fma2(a0.im, a0.im, zs));
    zs = fma2(a1.re, a1.re, fma2(a1.im, a1.im, zs));
    zs = fma2(a2.re, a2.re, fma2(a2.im, a2.im, zs));
    zs = fma2(a3.re, a3.re, fma2(a3.im, a3.im, zs));
    zs = fma2(a4.re, a4.re, fma2(a4.im, a4.im, zs));
    zs = fma2(a5.re, a5.re, fma2(a5.im, a5.im, zs));
    zs = fma2(a6.re, a6.re, fma2(a6.im, a6.im, zs));
    zs = fma2(a7.re, a7.re, fma2(a7.im, a7.im, zs));
    if (t & 256) zs = -zs;

    float za = zs.x, zb = zs.y;
    #pragma unroll
    for (int off = 32; off >= 1; off >>= 1) {
        za += __shfl_down(za, off);
        zb += __shfl_down(zb, off);
    }

    __syncthreads();                  // all pass-D reads done before st reuse
    float* red = (float*)st;
    if (lane == 0) { red[t >> 6] = za; red[8 + (t >> 6)] = zb; }
    __syncthreads();

    if (t == 0) {
        float zta = 0.0f, ztb = 0.0f;
        #pragma unroll
        for (int wv = 0; wv < 8; ++wv) { zta += red[wv]; ztb += red[8 + wv]; }
        out[2 * e0 + 0] = zta * hw[0] + hb[0];
        out[2 * e0 + 1] = zta * hw[1] + hb[1];
        out[2 * e0 + 2] = ztb * hw[0] + hb[0];
        out[2 * e0 + 3] = ztb * hw[1] + hb[1];
    }
}

extern "C" void kernel_launch(void* const* d_in, const int* in_sizes, int n_in,
                              void* d_out, int out_size, void* d_ws, size_t ws_size,
                              hipStream_t stream) {
    const float* x  = (const float*)d_in[0];
    const float* w  = (const float*)d_in[1];
    const float* hw = (const float*)d_in[2];
    const float* hb = (const float*)d_in[3];
    float* out = (float*)d_out;
    const int B = in_sizes[0] / NQ;   // 1024
    qsim_kernel<<<B / 2, TPB, 0, stream>>>(x, w, hw, hb, out);
}